// Round 12
// baseline (2375.952 us; speedup 1.0000x reference)
//
#include <hip/hip_runtime.h>
#include <math.h>

#define HW 25600
#define Wd 160
#define Hd 160
#define Bsz 4
#define Cc 128
#define Kk 179

__device__ __forceinline__ float silu_f(float y){ return y / (1.0f + expf(-y)); }

// XCD-aware swizzle: hardware assigns XCD = flat%8 (round-robin). Remap so each
// XCD's blocks cover a contiguous tile-slab with ALL co-groups -> L2 reuse.
// (r9: conv3x3 FETCH 215->43 MB)
__device__ __forceinline__ int xcd_swizzle(int flat, int nblk) {
    return (nblk >> 3) * (flat & 7) + (flat >> 3);
}

// ---------------- weight transposes (run once, tiny) ----------------
// [co][ci] -> wt[ci][co]
__global__ void wtr_mat_kernel(const float* __restrict__ w, float* __restrict__ wt,
                               int nco, int nci)
{
    const int ci = blockIdx.x;
    const int co = threadIdx.x;
    wt[(size_t)ci * nco + co] = w[(size_t)co * nci + ci];
}
// [co][ci][9] -> wt[ci][co][9]
__global__ void wtr3_kernel(const float* __restrict__ w, float* __restrict__ wt)
{
    const int ci = blockIdx.x;   // 128
    const int co = threadIdx.x;  // 128
#pragma unroll
    for (int t = 0; t < 9; ++t)
        wt[((size_t)ci * 128 + co) * 9 + t] = w[((size_t)co * 128 + ci) * 9 + t];
}

// ---------------- cv1: 1x1 conv 256->256 + SiLU ----------------
// weights TRANSPOSED: wt[ci][co] -> per (ci,j) the 16 co weights are contiguous.
__global__ __launch_bounds__(256) void cv1_kernel(
    const float* __restrict__ x, const float* __restrict__ wt,
    const float* __restrict__ bias, float* __restrict__ y0)
{
    const int flat = blockIdx.x + 16 * (blockIdx.y + 25 * blockIdx.z);
    const int wk = xcd_swizzle(flat, 1600);
    const int cog = wk & 15;
    const int rest = wk >> 4;          // 0..99
    const int pxb = rest % 25;
    const int b = rest / 25;

    const int t = threadIdx.x;
    const int p0 = pxb * 1024 + t * 4;
    const int co0 = cog * 16;
    const float* xb = x + (size_t)b * 256 * HW + p0;
    float4 acc[16];
#pragma unroll
    for (int k = 0; k < 16; ++k) acc[k] = make_float4(0.f, 0.f, 0.f, 0.f);

    for (int ci0 = 0; ci0 < 256; ci0 += 4) {
        float4 v[4];
#pragma unroll
        for (int j = 0; j < 4; ++j)
            v[j] = *(const float4*)(xb + (size_t)(ci0 + j) * HW);
#pragma unroll
        for (int j = 0; j < 4; ++j) {
            const float* wr = wt + (size_t)(ci0 + j) * 256 + co0;  // 16 contiguous
#pragma unroll
            for (int co = 0; co < 16; ++co) {
                float wv = wr[co];
                acc[co].x = fmaf(wv, v[j].x, acc[co].x);
                acc[co].y = fmaf(wv, v[j].y, acc[co].y);
                acc[co].z = fmaf(wv, v[j].z, acc[co].z);
                acc[co].w = fmaf(wv, v[j].w, acc[co].w);
            }
        }
    }
#pragma unroll
    for (int co = 0; co < 16; ++co) {
        float bv = bias[co0 + co];
        float4 a = acc[co];
        a.x = silu_f(a.x + bv); a.y = silu_f(a.y + bv);
        a.z = silu_f(a.z + bv); a.w = silu_f(a.w + bv);
        *(float4*)(y0 + ((size_t)b * 256 + co0 + co) * HW + p0) = a;
    }
}

// ---------------- 3x3 conv 128->128 (SiLU or aw-scale) ----------------
// r11 body + weights staged in LDS (2 chunks of 64 ci, 36KB): in-loop weight
// reads are wave-uniform ds_read broadcasts -> no scalar-cache misses.
#define WCHUNK 64
__global__ __launch_bounds__(256) void conv3x3_kernel(
    const float* __restrict__ in, long in_bstride,
    const float* __restrict__ wt, const float* __restrict__ bias,
    float* __restrict__ out, long out_bstride,
    const float* __restrict__ awp, int act)
{
    __shared__ float wl[WCHUNK * 144];   // 36864 B

    const int flat = blockIdx.x + 8 * (blockIdx.y + 25 * blockIdx.z);
    const int wk = xcd_swizzle(flat, 800);
    const int cog = wk & 7;
    const int rest = wk >> 3;          // 0..99
    const int tile = rest % 25;
    const int b = rest / 25;

    const int tid = threadIdx.x;
    const int ty = tid >> 3;           // 0..31
    const int tx0 = (tid & 7) * 4;     // 0..28
    const int x0 = (tile % 5) * 32;
    const int y0_ = (tile / 5) * 32;
    const int co0 = cog * 16;
    const int oy = y0_ + ty, ox = x0 + tx0;

    const float* inb = in + (size_t)b * in_bstride;

    int rb[3]; float mrow[3];
#pragma unroll
    for (int r = 0; r < 3; ++r) {
        int gy = oy + r - 1;
        mrow[r] = (gy >= 0 && gy < Hd) ? 1.f : 0.f;
        int gyc = gy < 0 ? 0 : (gy > Hd - 1 ? Hd - 1 : gy);
        rb[r] = gyc * Wd;
    }
    const float mc0 = (ox - 1 >= 0) ? 1.f : 0.f;
    const float mc5 = (ox + 4 < Wd) ? 1.f : 0.f;
    const int c0 = (ox - 1 >= 0) ? ox - 1 : 0;
    const int c5 = (ox + 4 < Wd) ? ox + 4 : Wd - 1;

    float4 acc[16];
#pragma unroll
    for (int k = 0; k < 16; ++k) acc[k] = make_float4(0.f, 0.f, 0.f, 0.f);

    for (int cb = 0; cb < 128; cb += WCHUNK) {
        if (cb) __syncthreads();   // protect LDS overwrite
        // stage this chunk's weights: wt[(cb+ci)*128+co0 ..+16][9] -> wl[ci*144..]
        for (int l = tid; l < WCHUNK * 36; l += 256) {
            int ci = l / 36, ro = (l % 36) * 4;
            *(float4*)&wl[ci * 144 + ro] =
                *(const float4*)&wt[((size_t)(cb + ci) * 128 + co0) * 9 + ro];
        }
        __syncthreads();

        for (int ci2 = 0; ci2 < WCHUNK; ++ci2) {
            const float* pc = inb + (size_t)(cb + ci2) * HW;
            float win[18];
#pragma unroll
            for (int r = 0; r < 3; ++r) {
                const float* rp = pc + rb[r];
                float4 mid = *(const float4*)(rp + ox);   // 16B aligned, in-bounds
                float mm = mrow[r];
                win[r * 6 + 0] = rp[c0] * (mm * mc0);
                win[r * 6 + 1] = mid.x * mm;
                win[r * 6 + 2] = mid.y * mm;
                win[r * 6 + 3] = mid.z * mm;
                win[r * 6 + 4] = mid.w * mm;
                win[r * 6 + 5] = rp[c5] * (mm * mc5);
            }
            const float* wc = &wl[ci2 * 144];   // 144 contiguous, wave-uniform
#pragma unroll
            for (int co = 0; co < 16; ++co) {
                const float* wr = wc + co * 9;
#pragma unroll
                for (int t = 0; t < 9; ++t) {
                    const int dy = t / 3, dx = t % 3;
                    float wv = wr[t];
                    acc[co].x = fmaf(wv, win[dy * 6 + dx + 0], acc[co].x);
                    acc[co].y = fmaf(wv, win[dy * 6 + dx + 1], acc[co].y);
                    acc[co].z = fmaf(wv, win[dy * 6 + dx + 2], acc[co].z);
                    acc[co].w = fmaf(wv, win[dy * 6 + dx + 3], acc[co].w);
                }
            }
        }
    }

    float4 awv = make_float4(1.f, 1.f, 1.f, 1.f);
    if (awp) awv = *(const float4*)(awp + b * HW + oy * Wd + ox);
#pragma unroll
    for (int co = 0; co < 16; ++co) {
        float bv = bias[co0 + co];
        float4 a = acc[co];
        a.x += bv; a.y += bv; a.z += bv; a.w += bv;
        if (act) {
            a.x = silu_f(a.x); a.y = silu_f(a.y);
            a.z = silu_f(a.z); a.w = silu_f(a.w);
        } else {
            a.x *= awv.x; a.y *= awv.y; a.z *= awv.z; a.w *= awv.w;
        }
        *(float4*)(out + (size_t)b * out_bstride + (size_t)(co0 + co) * HW + oy * Wd + ox) = a;
    }
}

// ---------------- g = guide @ gl_w.T + gl_b ----------------
__global__ void g_kernel(const float* __restrict__ guide, const float* __restrict__ glw,
                         const float* __restrict__ glb, float* __restrict__ g)
{
    const int bn = blockIdx.x;      // 0..63 (b*16+n)
    const int c = threadIdx.x;      // 0..127
    const float* gr = guide + (size_t)bn * 512;
    const float* wr = glw + (size_t)c * 512;
    float acc = 0.f;
    for (int k = 0; k < 512; ++k) acc += gr[k] * wr[k];
    g[bn * 128 + c] = acc + glb[c];
}

// ---------------- aw = sigmoid(max_n(m_out . g_n)/sqrt(C) + bias) ----------------
// grid (25, 4), block 256; thread owns 4 px
__global__ __launch_bounds__(256) void attn_kernel(
    const float* __restrict__ mo, const float* __restrict__ g,
    const float* __restrict__ ab, float* __restrict__ aw)
{
    const int p0 = blockIdx.x * 1024 + threadIdx.x * 4;
    const int b = blockIdx.y;
    __shared__ float gl[128 * 16];  // [c][n]
    for (int l = threadIdx.x; l < 2048; l += 256) {
        int n = l & 15, c = l >> 4;
        gl[l] = g[(b * 16 + n) * 128 + c];
    }
    __syncthreads();
    float4 acc[16];   // [n] x 4 px
#pragma unroll
    for (int n = 0; n < 16; ++n) acc[n] = make_float4(0.f, 0.f, 0.f, 0.f);
    const float* mb = mo + (size_t)b * 128 * HW + p0;
    for (int c = 0; c < 128; ++c) {
        float4 v = *(const float4*)(mb + (size_t)c * HW);
        const float4* g4 = (const float4*)(&gl[c * 16]);
#pragma unroll
        for (int n4 = 0; n4 < 4; ++n4) {
            float4 gv = g4[n4];
#pragma unroll
            for (int q = 0; q < 4; ++q) {
                float gw = (q == 0) ? gv.x : (q == 1) ? gv.y : (q == 2) ? gv.z : gv.w;
                float4& a = acc[n4 * 4 + q];
                a.x = fmaf(gw, v.x, a.x);
                a.y = fmaf(gw, v.y, a.y);
                a.z = fmaf(gw, v.z, a.z);
                a.w = fmaf(gw, v.w, a.w);
            }
        }
    }
    float4 m = acc[0];
#pragma unroll
    for (int n = 1; n < 16; ++n) {
        m.x = fmaxf(m.x, acc[n].x);
        m.y = fmaxf(m.y, acc[n].y);
        m.z = fmaxf(m.z, acc[n].z);
        m.w = fmaxf(m.w, acc[n].w);
    }
    const float s = 1.f / sqrtf(128.f);
    const float bb = ab[0];
    float4 r;
    r.x = 1.f / (1.f + expf(-(m.x * s + bb)));
    r.y = 1.f / (1.f + expf(-(m.y * s + bb)));
    r.z = 1.f / (1.f + expf(-(m.z * s + bb)));
    r.w = 1.f / (1.f + expf(-(m.w * s + bb)));
    *(float4*)(aw + b * HW + p0) = r;
}

// ---------------- cv2: 1x1 conv 512->256 + SiLU -> d_out ----------------
// weights TRANSPOSED: wt[ci(512)][co(256)]
__global__ __launch_bounds__(256) void cv2_kernel(
    const float* __restrict__ y0, const float* __restrict__ mo, const float* __restrict__ nw,
    const float* __restrict__ wt, const float* __restrict__ bias, float* __restrict__ out)
{
    const int flat = blockIdx.x + 16 * (blockIdx.y + 25 * blockIdx.z);
    const int wk = xcd_swizzle(flat, 1600);
    const int cog = wk & 15;
    const int rest = wk >> 4;          // 0..99
    const int pxb = rest % 25;
    const int b = rest / 25;

    const int t = threadIdx.x;
    const int p0 = pxb * 1024 + t * 4;
    const int co0 = cog * 16;
    float4 acc[16];
#pragma unroll
    for (int k = 0; k < 16; ++k) acc[k] = make_float4(0.f, 0.f, 0.f, 0.f);

    for (int blk = 0; blk < 4; ++blk) {
        const float* src;
        if (blk == 0)      src = y0 + (size_t)b * 256 * HW;
        else if (blk == 1) src = y0 + ((size_t)b * 256 + 128) * HW;
        else if (blk == 2) src = mo + (size_t)b * 128 * HW;
        else               src = nw + (size_t)b * 128 * HW;
        src += p0;
        for (int ci0 = 0; ci0 < 128; ci0 += 4) {
            float4 v[4];
#pragma unroll
            for (int j = 0; j < 4; ++j)
                v[j] = *(const float4*)(src + (size_t)(ci0 + j) * HW);
#pragma unroll
            for (int j = 0; j < 4; ++j) {
                const float* wr = wt + (size_t)(blk * 128 + ci0 + j) * 256 + co0;
#pragma unroll
                for (int co = 0; co < 16; ++co) {
                    float wv = wr[co];
                    acc[co].x = fmaf(wv, v[j].x, acc[co].x);
                    acc[co].y = fmaf(wv, v[j].y, acc[co].y);
                    acc[co].z = fmaf(wv, v[j].z, acc[co].z);
                    acc[co].w = fmaf(wv, v[j].w, acc[co].w);
                }
            }
        }
    }
#pragma unroll
    for (int co = 0; co < 16; ++co) {
        float bv = bias[co0 + co];
        float4 a = acc[co];
        a.x = silu_f(a.x + bv); a.y = silu_f(a.y + bv);
        a.z = silu_f(a.z + bv); a.w = silu_f(a.w + bv);
        *(float4*)(out + ((size_t)b * 256 + co0 + co) * HW + p0) = a;
    }
}

// ---------------- top-K radix select (per-batch block) ----------------
__global__ __launch_bounds__(1024) void topk_kernel(
    const float* __restrict__ aw, int* __restrict__ idx, int* __restrict__ ties)
{
    const int b = blockIdx.x;
    const float* v = aw + b * HW;
    __shared__ unsigned hist[256];
    __shared__ unsigned s_sel;
    __shared__ int s_rem;
    __shared__ int s_cnt, s_tcnt;
    const int tid = threadIdx.x;
    unsigned prefix = 0; int rem = Kk;
    for (int shift = 24; shift >= 0; shift -= 8) {
        if (tid < 256) hist[tid] = 0;
        __syncthreads();
        unsigned mask_hi = (shift == 24) ? 0u : ~((1u << (shift + 8)) - 1u);
        for (int i = tid; i < HW; i += 1024) {
            unsigned u = __float_as_uint(v[i]);
            if ((u & mask_hi) == (prefix & mask_hi))
                atomicAdd(&hist[(u >> shift) & 255], 1u);
        }
        __syncthreads();
        if (tid == 0) {
            int cum = 0; unsigned bsel = 0;
            for (int xq = 255; xq >= 0; --xq) {
                int h = (int)hist[xq];
                if (cum + h >= rem) { bsel = (unsigned)xq; break; }
                cum += h;
            }
            s_sel = bsel; s_rem = rem - cum;
        }
        __syncthreads();
        prefix |= (s_sel << shift);
        rem = s_rem;
        __syncthreads();
    }
    const unsigned T = prefix;
    if (tid == 0) { s_cnt = 0; s_tcnt = 0; }
    __syncthreads();
    for (int i = tid; i < HW; i += 1024) {
        unsigned u = __float_as_uint(v[i]);
        if (u > T)       { int p = atomicAdd(&s_cnt, 1);  idx[b * Kk + p] = i; }
        else if (u == T) { int p = atomicAdd(&s_tcnt, 1); ties[b * HW + p] = i; }
    }
    __syncthreads();
    if (tid == 0) {
        int base = s_cnt;
        int need = Kk - base;
        int tn = s_tcnt;
        int* tb = ties + b * HW;
        for (int s = 0; s < need; ++s) {
            int mn = 0x7fffffff, mi = -1;
            for (int t = 0; t < tn; ++t) if (tb[t] < mn) { mn = tb[t]; mi = t; }
            idx[b * Kk + base + s] = mn;
            if (mi >= 0) tb[mi] = 0x7fffffff;
        }
    }
}

// ---------------- gather + row norm ----------------
__global__ __launch_bounds__(256) void gather_kernel(
    const float* __restrict__ z, const int* __restrict__ idx,
    float* __restrict__ X, float* __restrict__ ninv)
{
    const int m = blockIdx.x;
    const int b = m / Kk;
    const int pix = idx[m];
    const int c = threadIdx.x;
    float v = z[((size_t)b * 256 + c) * HW + pix];
    X[(size_t)m * 256 + c] = v;
    float s = v * v;
#pragma unroll
    for (int o = 32; o; o >>= 1) s += __shfl_down(s, o, 64);
    __shared__ float red[4];
    if ((c & 63) == 0) red[c >> 6] = s;
    __syncthreads();
    if (c == 0) {
        float t = red[0] + red[1] + red[2] + red[3];
        float nr = sqrtf(t);
        ninv[m] = 1.f / fmaxf(nr, 1e-12f);
    }
}

// ---------------- adjacency A_hat + dinv ----------------
__global__ __launch_bounds__(256) void adj_kernel(
    const float* __restrict__ X, const float* __restrict__ ninv,
    float* __restrict__ Ah, float* __restrict__ dinv)
{
    const int i = blockIdx.x;
    const int tid = threadIdx.x;
    __shared__ float Xi[256];
    Xi[tid] = X[(size_t)i * 256 + tid];
    __syncthreads();
    const float ni = ninv[i];
    float rs = 0.f;
    for (int j = tid; j < 716; j += 256) {
        const float* Xj = X + (size_t)j * 256;
        float d = 0.f;
        for (int c = 0; c < 256; ++c) d += Xi[c] * Xj[c];
        float s = d * ni * ninv[j];
        float ah = (s > 0.5f) ? 1.f : 0.f;
        if (j == i) ah += 1.f;
        Ah[(size_t)i * 716 + j] = ah;
        rs += ah;
    }
#pragma unroll
    for (int o = 32; o; o >>= 1) rs += __shfl_down(rs, o, 64);
    __shared__ float red[4];
    if ((tid & 63) == 0) red[tid >> 6] = rs;
    __syncthreads();
    if (tid == 0) {
        float t = red[0] + red[1] + red[2] + red[3];
        dinv[i] = 1.f / sqrtf(t);
    }
}

// ---------------- Y1 = X @ W1 ----------------
__global__ void y1_kernel(const float* __restrict__ X, const float* __restrict__ w1,
                          float* __restrict__ Y1)
{
    const int i = blockIdx.x, co = threadIdx.x; // 64 threads
    const float* Xi = X + (size_t)i * 256;
    float acc = 0.f;
    for (int c = 0; c < 256; ++c) acc += Xi[c] * w1[c * 64 + co];
    Y1[i * 64 + co] = acc;
}

// ---------------- h1 = relu(An @ Y1 + b1) ----------------
__global__ void h1_kernel(const float* __restrict__ Ah, const float* __restrict__ dinv,
                          const float* __restrict__ Y1, const float* __restrict__ b1,
                          float* __restrict__ h1)
{
    const int i = blockIdx.x, co = threadIdx.x; // 64 threads
    float acc = 0.f;
    const float* Ar = Ah + (size_t)i * 716;
    for (int j = 0; j < 716; ++j) {
        float a = Ar[j];
        if (a != 0.f) acc += a * dinv[j] * Y1[j * 64 + co];
    }
    float vv = dinv[i] * acc + b1[co];
    h1[i * 64 + co] = fmaxf(vv, 0.f);
}

// ---------------- Y2 = h1 @ W2 ----------------
__global__ void y2_kernel(const float* __restrict__ h1, const float* __restrict__ w2,
                          float* __restrict__ Y2)
{
    const int i = blockIdx.x, co = threadIdx.x; // 256 threads
    const float* hi = h1 + (size_t)i * 64;
    float acc = 0.f;
    for (int c = 0; c < 64; ++c) acc += hi[c] * w2[c * 256 + co];
    Y2[i * 256 + co] = acc;
}

// ---------------- upd = An @ Y2 + b2, scatter into out ----------------
__global__ void upd_kernel(const float* __restrict__ Ah, const float* __restrict__ dinv,
                           const float* __restrict__ Y2, const float* __restrict__ b2,
                           const int* __restrict__ idx, float* __restrict__ out)
{
    const int i = blockIdx.x, co = threadIdx.x; // 256 threads
    const int b = i / Kk;
    const int pix = idx[i];
    float acc = 0.f;
    const float* Ar = Ah + (size_t)i * 716;
    for (int j = 0; j < 716; ++j) {
        float a = Ar[j];
        if (a != 0.f) acc += a * dinv[j] * Y2[(size_t)j * 256 + co];
    }
    out[((size_t)b * 256 + co) * HW + pix] = dinv[i] * acc + b2[co];
}

extern "C" void kernel_launch(void* const* d_in, const int* in_sizes, int n_in,
                              void* d_out, int out_size, void* d_ws, size_t ws_size,
                              hipStream_t stream) {
    const float* x     = (const float*)d_in[0];
    const float* guide = (const float*)d_in[1];
    const float* cv1w  = (const float*)d_in[2];
    const float* cv1b  = (const float*)d_in[3];
    const float* m1w   = (const float*)d_in[4];
    const float* m1b   = (const float*)d_in[5];
    const float* m2w   = (const float*)d_in[6];
    const float* m2b   = (const float*)d_in[7];
    const float* glw   = (const float*)d_in[8];
    const float* glb   = (const float*)d_in[9];
    const float* attb  = (const float*)d_in[10];
    const float* pw    = (const float*)d_in[11];
    const float* pb    = (const float*)d_in[12];
    const float* c2w   = (const float*)d_in[13];
    const float* c2b   = (const float*)d_in[14];
    const float* g1w   = (const float*)d_in[15];
    const float* g1b   = (const float*)d_in[16];
    const float* g2w   = (const float*)d_in[17];
    const float* g2b   = (const float*)d_in[18];
    float* out = (float*)d_out;

    char* ws = (char*)d_ws;
    size_t off = 0;
    auto alloc = [&](size_t bytes) -> void* {
        void* p = ws + off;
        off += (bytes + 255) & ~(size_t)255;
        return p;
    };
    float* y0   = (float*)alloc(sizeof(float) * (size_t)Bsz * 256 * HW);
    float* t1   = (float*)alloc(sizeof(float) * (size_t)Bsz * 128 * HW);
    float* mo   = (float*)alloc(sizeof(float) * (size_t)Bsz * 128 * HW);
    float* aw   = (float*)alloc(sizeof(float) * Bsz * HW);
    float* g    = (float*)alloc(sizeof(float) * 64 * 128);
    float* X    = (float*)alloc(sizeof(float) * 716 * 256);
    float* ninv = (float*)alloc(sizeof(float) * 716);
    float* Ah   = (float*)alloc(sizeof(float) * 716 * 716);
    float* dinv = (float*)alloc(sizeof(float) * 716);
    float* Y1   = (float*)alloc(sizeof(float) * 716 * 64);
    float* h1v  = (float*)alloc(sizeof(float) * 716 * 64);
    float* Y2   = (float*)alloc(sizeof(float) * 716 * 256);
    int* idx    = (int*)alloc(sizeof(int) * 716);
    int* ties   = (int*)alloc(sizeof(int) * (size_t)Bsz * HW);
    float* wt1  = (float*)alloc(sizeof(float) * 256 * 256);
    float* wt2  = (float*)alloc(sizeof(float) * 512 * 256);
    float* wtm1 = (float*)alloc(sizeof(float) * 128 * 128 * 9);
    float* wtm2 = (float*)alloc(sizeof(float) * 128 * 128 * 9);
    float* wtp  = (float*)alloc(sizeof(float) * 128 * 128 * 9);

    // weight transposes (tiny)
    wtr_mat_kernel<<<dim3(256), dim3(256), 0, stream>>>(cv1w, wt1, 256, 256);
    wtr_mat_kernel<<<dim3(512), dim3(256), 0, stream>>>(c2w, wt2, 256, 512);
    wtr3_kernel<<<dim3(128), dim3(128), 0, stream>>>(m1w, wtm1);
    wtr3_kernel<<<dim3(128), dim3(128), 0, stream>>>(m2w, wtm2);
    wtr3_kernel<<<dim3(128), dim3(128), 0, stream>>>(pw, wtp);

    g_kernel<<<dim3(64), dim3(128), 0, stream>>>(guide, glw, glb, g);
    cv1_kernel<<<dim3(16, 25, 4), dim3(256), 0, stream>>>(x, wt1, cv1b, y0);
    conv3x3_kernel<<<dim3(8, 25, 4), dim3(256), 0, stream>>>(
        y0 + (size_t)128 * HW, (long)256 * HW, wtm1, m1b, t1, (long)128 * HW, nullptr, 1);
    conv3x3_kernel<<<dim3(8, 25, 4), dim3(256), 0, stream>>>(
        t1, (long)128 * HW, wtm2, m2b, mo, (long)128 * HW, nullptr, 1);
    attn_kernel<<<dim3(25, 4), dim3(256), 0, stream>>>(mo, g, attb, aw);
    conv3x3_kernel<<<dim3(8, 25, 4), dim3(256), 0, stream>>>(
        mo, (long)128 * HW, wtp, pb, t1, (long)128 * HW, aw, 0);
    cv2_kernel<<<dim3(16, 25, 4), dim3(256), 0, stream>>>(y0, mo, t1, wt2, c2b, out);
    topk_kernel<<<dim3(4), dim3(1024), 0, stream>>>(aw, idx, ties);
    gather_kernel<<<dim3(716), dim3(256), 0, stream>>>(out, idx, X, ninv);
    adj_kernel<<<dim3(716), dim3(256), 0, stream>>>(X, ninv, Ah, dinv);
    y1_kernel<<<dim3(716), dim3(64), 0, stream>>>(X, g1w, Y1);
    h1_kernel<<<dim3(716), dim3(64), 0, stream>>>(Ah, dinv, Y1, g1b, h1v);
    y2_kernel<<<dim3(716), dim3(256), 0, stream>>>(h1v, g2w, Y2);
    upd_kernel<<<dim3(716), dim3(256), 0, stream>>>(Ah, dinv, Y2, g2b, idx, out);
}

// Round 13
// 1974.946 us; speedup vs baseline: 1.2030x; 1.2030x over previous
//
#include <hip/hip_runtime.h>
#include <math.h>

#define HW 25600
#define Wd 160
#define Hd 160
#define Bsz 4
#define Cc 128
#define Kk 179

__device__ __forceinline__ float silu_f(float y){ return y / (1.0f + expf(-y)); }

// XCD-aware swizzle (r9: conv3x3 FETCH 215->43 MB)
__device__ __forceinline__ int xcd_swizzle(int flat, int nblk) {
    return (nblk >> 3) * (flat & 7) + (flat >> 3);
}

// ---------------- weight transposes (run once, tiny) ----------------
// [co][ci] -> wt[ci][co]
__global__ void wtr_mat_kernel(const float* __restrict__ w, float* __restrict__ wt,
                               int nco, int nci)
{
    const int ci = blockIdx.x;
    const int co = threadIdx.x;
    wt[(size_t)ci * nco + co] = w[(size_t)co * nci + ci];
}
// three [co][ci][9] -> wt[ci][co][9] in one launch (grid.y selects matrix)
__global__ void wtr3_kernel(const float* __restrict__ s0, const float* __restrict__ s1,
                            const float* __restrict__ s2, float* __restrict__ d0,
                            float* __restrict__ d1, float* __restrict__ d2)
{
    const int ci = blockIdx.x;   // 128
    const int co = threadIdx.x;  // 128
    const int m = blockIdx.y;
    const float* w = (m == 0) ? s0 : (m == 1) ? s1 : s2;
    float* wt = (m == 0) ? d0 : (m == 1) ? d1 : d2;
#pragma unroll
    for (int t = 0; t < 9; ++t)
        wt[((size_t)ci * 128 + co) * 9 + t] = w[((size_t)co * 128 + ci) * 9 + t];
}

// ---------------- cv1: 1x1 conv 256->256 + SiLU ----------------
__global__ __launch_bounds__(256) void cv1_kernel(
    const float* __restrict__ x, const float* __restrict__ wt,
    const float* __restrict__ bias, float* __restrict__ y0)
{
    const int flat = blockIdx.x + 16 * (blockIdx.y + 25 * blockIdx.z);
    const int wk = xcd_swizzle(flat, 1600);
    const int cog = wk & 15;
    const int rest = wk >> 4;          // 0..99
    const int pxb = rest % 25;
    const int b = rest / 25;

    const int t = threadIdx.x;
    const int p0 = pxb * 1024 + t * 4;
    const int co0 = cog * 16;
    const float* xb = x + (size_t)b * 256 * HW + p0;
    float4 acc[16];
#pragma unroll
    for (int k = 0; k < 16; ++k) acc[k] = make_float4(0.f, 0.f, 0.f, 0.f);

    for (int ci0 = 0; ci0 < 256; ci0 += 4) {
        float4 v[4];
#pragma unroll
        for (int j = 0; j < 4; ++j)
            v[j] = *(const float4*)(xb + (size_t)(ci0 + j) * HW);
#pragma unroll
        for (int j = 0; j < 4; ++j) {
            const float* wr = wt + (size_t)(ci0 + j) * 256 + co0;  // 16 contiguous
#pragma unroll
            for (int co = 0; co < 16; ++co) {
                float wv = wr[co];
                acc[co].x = fmaf(wv, v[j].x, acc[co].x);
                acc[co].y = fmaf(wv, v[j].y, acc[co].y);
                acc[co].z = fmaf(wv, v[j].z, acc[co].z);
                acc[co].w = fmaf(wv, v[j].w, acc[co].w);
            }
        }
    }
#pragma unroll
    for (int co = 0; co < 16; ++co) {
        float bv = bias[co0 + co];
        float4 a = acc[co];
        a.x = silu_f(a.x + bv); a.y = silu_f(a.y + bv);
        a.z = silu_f(a.z + bv); a.w = silu_f(a.w + bv);
        *(float4*)(y0 + ((size_t)b * 256 + co0 + co) * HW + p0) = a;
    }
}

// ---------------- 3x3 conv 128->128 (SiLU or aw-scale) ----------------
// r11 body; tiles 16x32, 128-thread blocks -> 1600 blocks (finer tail).
__global__ __launch_bounds__(128) void conv3x3_kernel(
    const float* __restrict__ in, long in_bstride,
    const float* __restrict__ wt, const float* __restrict__ bias,
    float* __restrict__ out, long out_bstride,
    const float* __restrict__ awp, int act)
{
    const int flat = blockIdx.x + 8 * (blockIdx.y + 50 * blockIdx.z);
    const int wk = xcd_swizzle(flat, 1600);
    const int cog = wk & 7;
    const int rest = wk >> 3;          // 0..199
    const int tile = rest % 50;        // 0..49
    const int b = rest / 50;

    const int tid = threadIdx.x;       // 0..127
    const int ty = tid >> 3;           // 0..15
    const int tx0 = (tid & 7) * 4;     // 0..28
    const int x0 = (tile % 5) * 32;
    const int y0_ = (tile / 5) * 16;
    const int co0 = cog * 16;
    const int oy = y0_ + ty, ox = x0 + tx0;

    const float* inb = in + (size_t)b * in_bstride;

    int rb[3]; float mrow[3];
#pragma unroll
    for (int r = 0; r < 3; ++r) {
        int gy = oy + r - 1;
        mrow[r] = (gy >= 0 && gy < Hd) ? 1.f : 0.f;
        int gyc = gy < 0 ? 0 : (gy > Hd - 1 ? Hd - 1 : gy);
        rb[r] = gyc * Wd;
    }
    const float mc0 = (ox - 1 >= 0) ? 1.f : 0.f;
    const float mc5 = (ox + 4 < Wd) ? 1.f : 0.f;
    const int c0 = (ox - 1 >= 0) ? ox - 1 : 0;
    const int c5 = (ox + 4 < Wd) ? ox + 4 : Wd - 1;

    float4 acc[16];
#pragma unroll
    for (int k = 0; k < 16; ++k) acc[k] = make_float4(0.f, 0.f, 0.f, 0.f);

    for (int ci = 0; ci < 128; ++ci) {
        const float* pc = inb + (size_t)ci * HW;
        float win[18];
#pragma unroll
        for (int r = 0; r < 3; ++r) {
            const float* rp = pc + rb[r];
            float4 mid = *(const float4*)(rp + ox);   // 16B aligned, in-bounds
            float mm = mrow[r];
            win[r * 6 + 0] = rp[c0] * (mm * mc0);
            win[r * 6 + 1] = mid.x * mm;
            win[r * 6 + 2] = mid.y * mm;
            win[r * 6 + 3] = mid.z * mm;
            win[r * 6 + 4] = mid.w * mm;
            win[r * 6 + 5] = rp[c5] * (mm * mc5);
        }
        const float* wc = wt + ((size_t)ci * 128 + co0) * 9;  // 144 contiguous floats
#pragma unroll
        for (int co = 0; co < 16; ++co) {
            const float* wr = wc + co * 9;
#pragma unroll
            for (int t = 0; t < 9; ++t) {
                const int dy = t / 3, dx = t % 3;
                float wv = wr[t];
                acc[co].x = fmaf(wv, win[dy * 6 + dx + 0], acc[co].x);
                acc[co].y = fmaf(wv, win[dy * 6 + dx + 1], acc[co].y);
                acc[co].z = fmaf(wv, win[dy * 6 + dx + 2], acc[co].z);
                acc[co].w = fmaf(wv, win[dy * 6 + dx + 3], acc[co].w);
            }
        }
    }

    float4 awv = make_float4(1.f, 1.f, 1.f, 1.f);
    if (awp) awv = *(const float4*)(awp + b * HW + oy * Wd + ox);
#pragma unroll
    for (int co = 0; co < 16; ++co) {
        float bv = bias[co0 + co];
        float4 a = acc[co];
        a.x += bv; a.y += bv; a.z += bv; a.w += bv;
        if (act) {
            a.x = silu_f(a.x); a.y = silu_f(a.y);
            a.z = silu_f(a.z); a.w = silu_f(a.w);
        } else {
            a.x *= awv.x; a.y *= awv.y; a.z *= awv.z; a.w *= awv.w;
        }
        *(float4*)(out + (size_t)b * out_bstride + (size_t)(co0 + co) * HW + oy * Wd + ox) = a;
    }
}

// ---------------- g = guide @ gl_w.T + gl_b ----------------
__global__ void g_kernel(const float* __restrict__ guide, const float* __restrict__ glw,
                         const float* __restrict__ glb, float* __restrict__ g)
{
    const int bn = blockIdx.x;      // 0..63 (b*16+n)
    const int c = threadIdx.x;      // 0..127
    const float* gr = guide + (size_t)bn * 512;
    const float* wr = glw + (size_t)c * 512;
    float acc = 0.f;
    for (int k = 0; k < 512; ++k) acc += gr[k] * wr[k];
    g[bn * 128 + c] = acc + glb[c];
}

// ---------------- aw = sigmoid(max_n(m_out . g_n)/sqrt(C) + bias) ----------------
// grid (100, 4), block 256 (1 px/thread — r10 proven shape)
__global__ __launch_bounds__(256) void attn_kernel(
    const float* __restrict__ mo, const float* __restrict__ g,
    const float* __restrict__ ab, float* __restrict__ aw)
{
    const int p = blockIdx.x * 256 + threadIdx.x;
    const int b = blockIdx.y;
    __shared__ float gl[128 * 16];  // [c][n]
    for (int l = threadIdx.x; l < 2048; l += 256) {
        int n = l & 15, c = l >> 4;
        gl[l] = g[(b * 16 + n) * 128 + c];
    }
    __syncthreads();
    float acc[16];
#pragma unroll
    for (int n = 0; n < 16; ++n) acc[n] = 0.f;
    const float* mb = mo + (size_t)b * 128 * HW + p;
    for (int c = 0; c < 128; ++c) {
        float v = mb[(size_t)c * HW];
        const float4* g4 = (const float4*)(&gl[c * 16]);
#pragma unroll
        for (int n4 = 0; n4 < 4; ++n4) {
            float4 gv = g4[n4];
            acc[n4 * 4 + 0] += v * gv.x;
            acc[n4 * 4 + 1] += v * gv.y;
            acc[n4 * 4 + 2] += v * gv.z;
            acc[n4 * 4 + 3] += v * gv.w;
        }
    }
    float m = acc[0];
#pragma unroll
    for (int n = 1; n < 16; ++n) m = fmaxf(m, acc[n]);
    float logit = m / sqrtf(128.f) + ab[0];
    aw[b * HW + p] = 1.f / (1.f + expf(-logit));
}

// ---------------- cv2: 1x1 conv 512->256 + SiLU -> d_out ----------------
__global__ __launch_bounds__(256) void cv2_kernel(
    const float* __restrict__ y0, const float* __restrict__ mo, const float* __restrict__ nw,
    const float* __restrict__ wt, const float* __restrict__ bias, float* __restrict__ out)
{
    const int flat = blockIdx.x + 16 * (blockIdx.y + 25 * blockIdx.z);
    const int wk = xcd_swizzle(flat, 1600);
    const int cog = wk & 15;
    const int rest = wk >> 4;          // 0..99
    const int pxb = rest % 25;
    const int b = rest / 25;

    const int t = threadIdx.x;
    const int p0 = pxb * 1024 + t * 4;
    const int co0 = cog * 16;
    float4 acc[16];
#pragma unroll
    for (int k = 0; k < 16; ++k) acc[k] = make_float4(0.f, 0.f, 0.f, 0.f);

    for (int blk = 0; blk < 4; ++blk) {
        const float* src;
        if (blk == 0)      src = y0 + (size_t)b * 256 * HW;
        else if (blk == 1) src = y0 + ((size_t)b * 256 + 128) * HW;
        else if (blk == 2) src = mo + (size_t)b * 128 * HW;
        else               src = nw + (size_t)b * 128 * HW;
        src += p0;
        for (int ci0 = 0; ci0 < 128; ci0 += 4) {
            float4 v[4];
#pragma unroll
            for (int j = 0; j < 4; ++j)
                v[j] = *(const float4*)(src + (size_t)(ci0 + j) * HW);
#pragma unroll
            for (int j = 0; j < 4; ++j) {
                const float* wr = wt + (size_t)(blk * 128 + ci0 + j) * 256 + co0;
#pragma unroll
                for (int co = 0; co < 16; ++co) {
                    float wv = wr[co];
                    acc[co].x = fmaf(wv, v[j].x, acc[co].x);
                    acc[co].y = fmaf(wv, v[j].y, acc[co].y);
                    acc[co].z = fmaf(wv, v[j].z, acc[co].z);
                    acc[co].w = fmaf(wv, v[j].w, acc[co].w);
                }
            }
        }
    }
#pragma unroll
    for (int co = 0; co < 16; ++co) {
        float bv = bias[co0 + co];
        float4 a = acc[co];
        a.x = silu_f(a.x + bv); a.y = silu_f(a.y + bv);
        a.z = silu_f(a.z + bv); a.w = silu_f(a.w + bv);
        *(float4*)(out + ((size_t)b * 256 + co0 + co) * HW + p0) = a;
    }
}

// ---------------- top-K radix select (per-batch block) ----------------
__global__ __launch_bounds__(1024) void topk_kernel(
    const float* __restrict__ aw, int* __restrict__ idx, int* __restrict__ ties)
{
    const int b = blockIdx.x;
    const float* v = aw + b * HW;
    __shared__ unsigned hist[256];
    __shared__ unsigned s_sel;
    __shared__ int s_rem;
    __shared__ int s_cnt, s_tcnt;
    const int tid = threadIdx.x;
    unsigned prefix = 0; int rem = Kk;
    for (int shift = 24; shift >= 0; shift -= 8) {
        if (tid < 256) hist[tid] = 0;
        __syncthreads();
        unsigned mask_hi = (shift == 24) ? 0u : ~((1u << (shift + 8)) - 1u);
        for (int i = tid; i < HW; i += 1024) {
            unsigned u = __float_as_uint(v[i]);
            if ((u & mask_hi) == (prefix & mask_hi))
                atomicAdd(&hist[(u >> shift) & 255], 1u);
        }
        __syncthreads();
        if (tid == 0) {
            int cum = 0; unsigned bsel = 0;
            for (int xq = 255; xq >= 0; --xq) {
                int h = (int)hist[xq];
                if (cum + h >= rem) { bsel = (unsigned)xq; break; }
                cum += h;
            }
            s_sel = bsel; s_rem = rem - cum;
        }
        __syncthreads();
        prefix |= (s_sel << shift);
        rem = s_rem;
        __syncthreads();
    }
    const unsigned T = prefix;
    if (tid == 0) { s_cnt = 0; s_tcnt = 0; }
    __syncthreads();
    for (int i = tid; i < HW; i += 1024) {
        unsigned u = __float_as_uint(v[i]);
        if (u > T)       { int p = atomicAdd(&s_cnt, 1);  idx[b * Kk + p] = i; }
        else if (u == T) { int p = atomicAdd(&s_tcnt, 1); ties[b * HW + p] = i; }
    }
    __syncthreads();
    if (tid == 0) {
        int base = s_cnt;
        int need = Kk - base;
        int tn = s_tcnt;
        int* tb = ties + b * HW;
        for (int s = 0; s < need; ++s) {
            int mn = 0x7fffffff, mi = -1;
            for (int t = 0; t < tn; ++t) if (tb[t] < mn) { mn = tb[t]; mi = t; }
            idx[b * Kk + base + s] = mn;
            if (mi >= 0) tb[mi] = 0x7fffffff;
        }
    }
}

// ---------------- gather + row norm ----------------
__global__ __launch_bounds__(256) void gather_kernel(
    const float* __restrict__ z, const int* __restrict__ idx,
    float* __restrict__ X, float* __restrict__ ninv)
{
    const int m = blockIdx.x;
    const int b = m / Kk;
    const int pix = idx[m];
    const int c = threadIdx.x;
    float v = z[((size_t)b * 256 + c) * HW + pix];
    X[(size_t)m * 256 + c] = v;
    float s = v * v;
#pragma unroll
    for (int o = 32; o; o >>= 1) s += __shfl_down(s, o, 64);
    __shared__ float red[4];
    if ((c & 63) == 0) red[c >> 6] = s;
    __syncthreads();
    if (c == 0) {
        float t = red[0] + red[1] + red[2] + red[3];
        float nr = sqrtf(t);
        ninv[m] = 1.f / fmaxf(nr, 1e-12f);
    }
}

// ---------------- adjacency A_hat + dinv ----------------
__global__ __launch_bounds__(256) void adj_kernel(
    const float* __restrict__ X, const float* __restrict__ ninv,
    float* __restrict__ Ah, float* __restrict__ dinv)
{
    const int i = blockIdx.x;
    const int tid = threadIdx.x;
    __shared__ float Xi[256];
    Xi[tid] = X[(size_t)i * 256 + tid];
    __syncthreads();
    const float ni = ninv[i];
    float rs = 0.f;
    for (int j = tid; j < 716; j += 256) {
        const float* Xj = X + (size_t)j * 256;
        float d = 0.f;
        for (int c = 0; c < 256; ++c) d += Xi[c] * Xj[c];
        float s = d * ni * ninv[j];
        float ah = (s > 0.5f) ? 1.f : 0.f;
        if (j == i) ah += 1.f;
        Ah[(size_t)i * 716 + j] = ah;
        rs += ah;
    }
#pragma unroll
    for (int o = 32; o; o >>= 1) rs += __shfl_down(rs, o, 64);
    __shared__ float red[4];
    if ((tid & 63) == 0) red[tid >> 6] = rs;
    __syncthreads();
    if (tid == 0) {
        float t = red[0] + red[1] + red[2] + red[3];
        dinv[i] = 1.f / sqrtf(t);
    }
}

// ---------------- Y1 = X @ W1 ----------------
__global__ void y1_kernel(const float* __restrict__ X, const float* __restrict__ w1,
                          float* __restrict__ Y1)
{
    const int i = blockIdx.x, co = threadIdx.x; // 64 threads
    const float* Xi = X + (size_t)i * 256;
    float acc = 0.f;
    for (int c = 0; c < 256; ++c) acc += Xi[c] * w1[c * 64 + co];
    Y1[i * 64 + co] = acc;
}

// ---------------- h1 = relu(An @ Y1 + b1) ----------------
__global__ void h1_kernel(const float* __restrict__ Ah, const float* __restrict__ dinv,
                          const float* __restrict__ Y1, const float* __restrict__ b1,
                          float* __restrict__ h1)
{
    const int i = blockIdx.x, co = threadIdx.x; // 64 threads
    float acc = 0.f;
    const float* Ar = Ah + (size_t)i * 716;
    for (int j = 0; j < 716; ++j) {
        float a = Ar[j];
        if (a != 0.f) acc += a * dinv[j] * Y1[j * 64 + co];
    }
    float vv = dinv[i] * acc + b1[co];
    h1[i * 64 + co] = fmaxf(vv, 0.f);
}

// ---------------- Y2 = h1 @ W2 ----------------
__global__ void y2_kernel(const float* __restrict__ h1, const float* __restrict__ w2,
                          float* __restrict__ Y2)
{
    const int i = blockIdx.x, co = threadIdx.x; // 256 threads
    const float* hi = h1 + (size_t)i * 64;
    float acc = 0.f;
    for (int c = 0; c < 64; ++c) acc += hi[c] * w2[c * 256 + co];
    Y2[i * 256 + co] = acc;
}

// ---------------- upd = An @ Y2 + b2, scatter into out ----------------
__global__ void upd_kernel(const float* __restrict__ Ah, const float* __restrict__ dinv,
                           const float* __restrict__ Y2, const float* __restrict__ b2,
                           const int* __restrict__ idx, float* __restrict__ out)
{
    const int i = blockIdx.x, co = threadIdx.x; // 256 threads
    const int b = i / Kk;
    const int pix = idx[i];
    float acc = 0.f;
    const float* Ar = Ah + (size_t)i * 716;
    for (int j = 0; j < 716; ++j) {
        float a = Ar[j];
        if (a != 0.f) acc += a * dinv[j] * Y2[(size_t)j * 256 + co];
    }
    out[((size_t)b * 256 + co) * HW + pix] = dinv[i] * acc + b2[co];
}

extern "C" void kernel_launch(void* const* d_in, const int* in_sizes, int n_in,
                              void* d_out, int out_size, void* d_ws, size_t ws_size,
                              hipStream_t stream) {
    const float* x     = (const float*)d_in[0];
    const float* guide = (const float*)d_in[1];
    const float* cv1w  = (const float*)d_in[2];
    const float* cv1b  = (const float*)d_in[3];
    const float* m1w   = (const float*)d_in[4];
    const float* m1b   = (const float*)d_in[5];
    const float* m2w   = (const float*)d_in[6];
    const float* m2b   = (const float*)d_in[7];
    const float* glw   = (const float*)d_in[8];
    const float* glb   = (const float*)d_in[9];
    const float* attb  = (const float*)d_in[10];
    const float* pw    = (const float*)d_in[11];
    const float* pb    = (const float*)d_in[12];
    const float* c2w   = (const float*)d_in[13];
    const float* c2b   = (const float*)d_in[14];
    const float* g1w   = (const float*)d_in[15];
    const float* g1b   = (const float*)d_in[16];
    const float* g2w   = (const float*)d_in[17];
    const float* g2b   = (const float*)d_in[18];
    float* out = (float*)d_out;

    char* ws = (char*)d_ws;
    size_t off = 0;
    auto alloc = [&](size_t bytes) -> void* {
        void* p = ws + off;
        off += (bytes + 255) & ~(size_t)255;
        return p;
    };
    float* y0   = (float*)alloc(sizeof(float) * (size_t)Bsz * 256 * HW);
    float* t1   = (float*)alloc(sizeof(float) * (size_t)Bsz * 128 * HW);
    float* mo   = (float*)alloc(sizeof(float) * (size_t)Bsz * 128 * HW);
    float* aw   = (float*)alloc(sizeof(float) * Bsz * HW);
    float* g    = (float*)alloc(sizeof(float) * 64 * 128);
    float* X    = (float*)alloc(sizeof(float) * 716 * 256);
    float* ninv = (float*)alloc(sizeof(float) * 716);
    float* Ah   = (float*)alloc(sizeof(float) * 716 * 716);
    float* dinv = (float*)alloc(sizeof(float) * 716);
    float* Y1   = (float*)alloc(sizeof(float) * 716 * 64);
    float* h1v  = (float*)alloc(sizeof(float) * 716 * 64);
    float* Y2   = (float*)alloc(sizeof(float) * 716 * 256);
    int* idx    = (int*)alloc(sizeof(int) * 716);
    int* ties   = (int*)alloc(sizeof(int) * (size_t)Bsz * HW);
    float* wt1  = (float*)alloc(sizeof(float) * 256 * 256);
    float* wt2  = (float*)alloc(sizeof(float) * 512 * 256);
    float* wtm1 = (float*)alloc(sizeof(float) * 128 * 128 * 9);
    float* wtm2 = (float*)alloc(sizeof(float) * 128 * 128 * 9);
    float* wtp  = (float*)alloc(sizeof(float) * 128 * 128 * 9);

    // weight transposes (tiny)
    wtr_mat_kernel<<<dim3(256), dim3(256), 0, stream>>>(cv1w, wt1, 256, 256);
    wtr_mat_kernel<<<dim3(512), dim3(256), 0, stream>>>(c2w, wt2, 256, 512);
    wtr3_kernel<<<dim3(128, 3), dim3(128), 0, stream>>>(m1w, m2w, pw, wtm1, wtm2, wtp);

    g_kernel<<<dim3(64), dim3(128), 0, stream>>>(guide, glw, glb, g);
    cv1_kernel<<<dim3(16, 25, 4), dim3(256), 0, stream>>>(x, wt1, cv1b, y0);
    conv3x3_kernel<<<dim3(8, 50, 4), dim3(128), 0, stream>>>(
        y0 + (size_t)128 * HW, (long)256 * HW, wtm1, m1b, t1, (long)128 * HW, nullptr, 1);
    conv3x3_kernel<<<dim3(8, 50, 4), dim3(128), 0, stream>>>(
        t1, (long)128 * HW, wtm2, m2b, mo, (long)128 * HW, nullptr, 1);
    attn_kernel<<<dim3(100, 4), dim3(256), 0, stream>>>(mo, g, attb, aw);
    conv3x3_kernel<<<dim3(8, 50, 4), dim3(128), 0, stream>>>(
        mo, (long)128 * HW, wtp, pb, t1, (long)128 * HW, aw, 0);
    cv2_kernel<<<dim3(16, 25, 4), dim3(256), 0, stream>>>(y0, mo, t1, wt2, c2b, out);
    topk_kernel<<<dim3(4), dim3(1024), 0, stream>>>(aw, idx, ties);
    gather_kernel<<<dim3(716), dim3(256), 0, stream>>>(out, idx, X, ninv);
    adj_kernel<<<dim3(716), dim3(256), 0, stream>>>(X, ninv, Ah, dinv);
    y1_kernel<<<dim3(716), dim3(64), 0, stream>>>(X, g1w, Y1);
    h1_kernel<<<dim3(716), dim3(64), 0, stream>>>(Ah, dinv, Y1, g1b, h1v);
    y2_kernel<<<dim3(716), dim3(256), 0, stream>>>(h1v, g2w, Y2);
    upd_kernel<<<dim3(716), dim3(256), 0, stream>>>(Ah, dinv, Y2, g2b, idx, out);
}